// Round 5
// baseline (440.576 us; speedup 1.0000x reference)
//
#include <hip/hip_runtime.h>
#include <cstdint>

// ---------------------------------------------------------------------------
// ATSS post-processor v3: contiguous-scan two-pass exact top-1000 selection
// (histogram threshold -> compact -> bitonic sort) + greedy class-aware NMS.
//
static constexpr int NI   = 8;
static constexpr int CC   = 80;
static constexpr int HH   = 160;
static constexpr int WW   = 160;
static constexpr int LL   = HH * WW;     // 25600
static constexpr int PRE_K  = 1000;
static constexpr int POST_K = 100;
static constexpr int CAP    = 32768;     // per-image candidate capacity
static constexpr int HSIZE  = 2048;      // top-13-bit score histogram
static constexpr int LPB2   = 12800;     // floats per scan block (half class slab)
static constexpr int NIT    = 13;        // ceil(12800 / 1024)
static constexpr int BPI3   = CC * 2;    // 160 scan blocks per image
static constexpr float PRE_T = 0.05f;
static constexpr float NMS_T = 0.6f;
static constexpr float CLIPV = 4.135166556742356f;   // log(1000/16)
static constexpr float IMGM1 = 1279.0f;

__device__ __forceinline__ float sigm(float x) { return 1.0f / (1.0f + expf(-x)); }

// ---------------------------------------------------------------------------
// K0: precompute cv = sigmoid(centerness) (0.8 MB, stays L2/L3 resident) and
// zero the histogram + counters (replaces hipMemsetAsync dispatch).
__global__ __launch_bounds__(256) void k_ctr(const float* __restrict__ ctr,
                                             float* __restrict__ cv,
                                             uint32_t* __restrict__ gz) {
    const int g = blockIdx.x * 256 + threadIdx.x;   // 64*256 = 16384 threads
    // zero ghist (NI*HSIZE words) + cnt (NI words)
    for (int i = g; i < NI * HSIZE + NI; i += 64 * 256) gz[i] = 0u;
    // sigmoid of 204800 floats as float4
    for (int i = g; i < (NI * LL) / 4; i += 64 * 256) {
        float4 x = ((const float4*)ctr)[i];
        float4 y = { sigm(x.x), sigm(x.y), sigm(x.z), sigm(x.w) };
        ((float4*)cv)[i] = y;
    }
}

// ---------------------------------------------------------------------------
// K1: histogram of candidate score bits (top 13). Block = one contiguous
// 12800-float slab of one (image, class). Loads batched 4-deep; the block
// reads one contiguous 4 KB line per sub-iteration.
__global__ __launch_bounds__(256) void k_hist(const float* __restrict__ cls,
                                              const float* __restrict__ cv,
                                              uint32_t* __restrict__ ghist) {
    __shared__ uint32_t h[4][HSIZE];
    const int t = threadIdx.x;
    for (int i = t; i < 4 * HSIZE; i += 256) (&h[0][0])[i] = 0u;
    __syncthreads();
    const int blk = blockIdx.x;
    const int n = blk / BPI3, rem = blk % BPI3, c = rem >> 1, half = rem & 1;
    const float* src = cls + ((size_t)n * CC + c) * LL + half * LPB2;
    const float* cvs = cv + (size_t)n * LL + half * LPB2;
    uint32_t* hw = h[t >> 6];
#pragma unroll 1
    for (int bi = 0; bi < NIT; bi += 4) {
        float4 xc[4], xv[4];
        int fo[4];
#pragma unroll
        for (int u = 0; u < 4; ++u) {
            int i = bi + u;
            int f = i * 1024 + t * 4;
            bool ok = (i < NIT) && (f < LPB2);
            fo[u] = ok ? f : -1;
            int fs = ok ? f : 0;
            xc[u] = *(const float4*)&src[fs];
            xv[u] = *(const float4*)&cvs[fs];
        }
#pragma unroll
        for (int u = 0; u < 4; ++u) {
            if (fo[u] < 0) continue;
            float p[4] = { sigm(xc[u].x), sigm(xc[u].y), sigm(xc[u].z), sigm(xc[u].w) };
            float v[4] = { xv[u].x, xv[u].y, xv[u].z, xv[u].w };
#pragma unroll
            for (int k = 0; k < 4; ++k) {
                if (p[k] > PRE_T)
                    atomicAdd(&hw[__float_as_uint(p[k] * v[k]) >> 19], 1u);
            }
        }
    }
    __syncthreads();
    for (int b = t; b < HSIZE; b += 256) {
        uint32_t s = h[0][b] + h[1][b] + h[2][b] + h[3][b];
        if (s) atomicAdd(&ghist[n * HSIZE + b], s);
    }
}

// ---------------------------------------------------------------------------
// K2: per image find highest bucket T with suffix-count >= PRE_K.
__global__ __launch_bounds__(256) void k_thresh(const uint32_t* __restrict__ ghist,
                                                uint32_t* __restrict__ thresh) {
    __shared__ uint32_t h[HSIZE];
    __shared__ uint32_t chunk[256];
    const int n = blockIdx.x, t = threadIdx.x;
    for (int b = t; b < HSIZE; b += 256) h[b] = ghist[n * HSIZE + b];
    __syncthreads();
    uint32_t s = 0;
    for (int k = 0; k < 8; ++k) s += h[t * 8 + k];
    chunk[t] = s;
    __syncthreads();
    if (t == 0) {
        uint32_t cum = 0;
        int T = 0;
        for (int c = 255; c >= 0; --c) {
            if (cum + chunk[c] >= (uint32_t)PRE_K) {
                for (int b = c * 8 + 7; b >= c * 8; --b) {
                    cum += h[b];
                    if (cum >= (uint32_t)PRE_K) { T = b; break; }
                }
                break;
            }
            cum += chunk[c];
        }
        thresh[n] = ((uint32_t)T) << 19;
    }
}

// ---------------------------------------------------------------------------
// K3: compact candidates >= threshold into keys (score_bits<<32 | ~flat_idx).
// Same contiguous blocking as k_hist.
__global__ __launch_bounds__(256) void k_collect(const float* __restrict__ cls,
                                                 const float* __restrict__ cv,
                                                 const uint32_t* __restrict__ thresh,
                                                 uint32_t* __restrict__ cnt,
                                                 unsigned long long* __restrict__ cand) {
    const int t = threadIdx.x;
    const int blk = blockIdx.x;
    const int n = blk / BPI3, rem = blk % BPI3, c = rem >> 1, half = rem & 1;
    const uint32_t th = thresh[n];
    const float* src = cls + ((size_t)n * CC + c) * LL + half * LPB2;
    const float* cvs = cv + (size_t)n * LL + half * LPB2;
#pragma unroll 1
    for (int bi = 0; bi < NIT; bi += 4) {
        float4 xc[4], xv[4];
        int fo[4];
#pragma unroll
        for (int u = 0; u < 4; ++u) {
            int i = bi + u;
            int f = i * 1024 + t * 4;
            bool ok = (i < NIT) && (f < LPB2);
            fo[u] = ok ? f : -1;
            int fs = ok ? f : 0;
            xc[u] = *(const float4*)&src[fs];
            xv[u] = *(const float4*)&cvs[fs];
        }
#pragma unroll
        for (int u = 0; u < 4; ++u) {
            if (fo[u] < 0) continue;
            float p[4] = { sigm(xc[u].x), sigm(xc[u].y), sigm(xc[u].z), sigm(xc[u].w) };
            float v[4] = { xv[u].x, xv[u].y, xv[u].z, xv[u].w };
#pragma unroll
            for (int k = 0; k < 4; ++k) {
                if (p[k] > PRE_T) {
                    uint32_t bits = __float_as_uint(p[k] * v[k]);
                    if (bits >= th) {
                        uint32_t pos = atomicAdd(&cnt[n], 1u);
                        if (pos < (uint32_t)CAP) {
                            uint32_t l = (uint32_t)(half * LPB2 + fo[u] + k);
                            uint32_t idx = l * (uint32_t)CC + (uint32_t)c;
                            cand[(size_t)n * CAP + pos] =
                                ((unsigned long long)bits << 32) | (uint32_t)(~idx);
                        }
                    }
                }
            }
        }
    }
}

// ---------------------------------------------------------------------------
// full descending bitonic sort of buf[0..2047] by a 1024-thread block.
__device__ __forceinline__ void sort2048(unsigned long long* buf, int t) {
    for (int k = 2; k <= 2048; k <<= 1) {
        for (int j = k >> 1; j > 0; j >>= 1) {
            __syncthreads();
#pragma unroll
            for (int u = 0; u < 2; ++u) {
                int i = t + u * 1024;
                int ixj = i ^ j;
                if (ixj > i) {
                    unsigned long long a = buf[i], b = buf[ixj];
                    bool desc = ((i & k) == 0);
                    if (desc ? (a < b) : (a > b)) { buf[i] = b; buf[ixj] = a; }
                }
            }
        }
    }
    __syncthreads();
}

// ---------------------------------------------------------------------------
// K4: sort top-2048 keys (usually M<=2048 -> single sort), decode boxes into
// SoA workspace arrays for the NMS kernel.
__global__ __launch_bounds__(1024) void k_select(const unsigned long long* __restrict__ cand,
                                                 const uint32_t* __restrict__ cnt,
                                                 const float* __restrict__ reg,
                                                 const float* __restrict__ anch,
                                                 float* __restrict__ X1, float* __restrict__ Y1,
                                                 float* __restrict__ X2, float* __restrict__ Y2,
                                                 float* __restrict__ AR, float* __restrict__ SC,
                                                 int* __restrict__ CL) {
    __shared__ unsigned long long buf[2048];
    const int n = blockIdx.x, t = threadIdx.x;
    uint32_t M = cnt[n];
    if (M > (uint32_t)CAP) M = CAP;
    buf[t]        = ((uint32_t)t < M)          ? cand[(size_t)n * CAP + t]        : 0ULL;
    buf[1024 + t] = ((uint32_t)(1024 + t) < M) ? cand[(size_t)n * CAP + 1024 + t] : 0ULL;
    sort2048(buf, t);
    for (uint32_t s = 2048; s < M; s += 1024) {   // rare overflow path
        buf[1024 + t] = (s + t < M) ? cand[(size_t)n * CAP + s + t] : 0ULL;
        sort2048(buf, t);
    }
    // decode epilogue
    const unsigned long long key = buf[t];
    const int gi = n * 1024 + t;
    if (key == 0ULL) {
        X1[gi] = 0.f; Y1[gi] = 0.f; X2[gi] = 0.f; Y2[gi] = 0.f;
        AR[gi] = 0.f; SC[gi] = 0.f; CL[gi] = 0;
    } else {
        uint32_t bits = (uint32_t)(key >> 32);
        uint32_t idx = ~(uint32_t)key;
        int l = (int)(idx / (uint32_t)CC);
        int c = (int)(idx % (uint32_t)CC);
        float4 a = *(const float4*)&anch[l * 4];
        float r0 = reg[((size_t)n * 4 + 0) * LL + l];
        float r1 = reg[((size_t)n * 4 + 1) * LL + l];
        float r2 = reg[((size_t)n * 4 + 2) * LL + l];
        float r3 = reg[((size_t)n * 4 + 3) * LL + l];
        float w  = a.z - a.x + 1.0f;
        float h  = a.w - a.y + 1.0f;
        float cx = a.x + 0.5f * w;
        float cy = a.y + 0.5f * h;
        float dx = r0 / 10.0f, dy = r1 / 10.0f;
        float dw = fminf(r2 / 5.0f, CLIPV), dh = fminf(r3 / 5.0f, CLIPV);
        float pcx = dx * w + cx, pcy = dy * h + cy;
        float pw = expf(dw) * w, ph = expf(dh) * h;
        float x1 = pcx - 0.5f * (pw - 1.0f);
        float y1 = pcy - 0.5f * (ph - 1.0f);
        float x2 = pcx + 0.5f * (pw - 1.0f);
        float y2 = pcy + 0.5f * (ph - 1.0f);
        x1 = fminf(fmaxf(x1, 0.0f), IMGM1);
        y1 = fminf(fmaxf(y1, 0.0f), IMGM1);
        x2 = fminf(fmaxf(x2, 0.0f), IMGM1);
        y2 = fminf(fmaxf(y2, 0.0f), IMGM1);
        X1[gi] = x1; Y1[gi] = y1; X2[gi] = x2; Y2[gi] = y2;
        AR[gi] = fmaxf(x2 - x1, 0.0f) * fmaxf(y2 - y1, 0.0f);
        SC[gi] = sqrtf(__uint_as_float(bits));
        CL[gi] = c + 1;
    }
}

// ---------------------------------------------------------------------------
// K5: greedy class-aware NMS (256 threads, 4 candidates each, early exit at
// 100 kept -- suppression only flows forward so this is exact) + output.
__global__ __launch_bounds__(256) void k_nms(const float* __restrict__ X1, const float* __restrict__ Y1,
                                             const float* __restrict__ X2, const float* __restrict__ Y2,
                                             const float* __restrict__ AR, const float* __restrict__ SC,
                                             const int* __restrict__ CL,
                                             float* __restrict__ out) {
    __shared__ float bx0[PRE_K], bx1[PRE_K], bx2[PRE_K], bx3[PRE_K];
    __shared__ float ar[PRE_K], scv[PRE_K];
    __shared__ int clsA[PRE_K], sup[PRE_K];
    __shared__ int s_kept;
    __shared__ int s_list[POST_K];
    const int n = blockIdx.x, t = threadIdx.x;
    if (t == 0) s_kept = 0;
    for (int i = t; i < PRE_K; i += 256) {
        const int gi = n * 1024 + i;
        bx0[i] = X1[gi]; bx1[i] = Y1[gi]; bx2[i] = X2[gi]; bx3[i] = Y2[gi];
        ar[i] = AR[gi]; scv[i] = SC[gi];
        int c = CL[gi];
        clsA[i] = c;
        sup[i] = (c == 0) ? 2 : 0;
    }
    __syncthreads();
    for (int i = 0; i < PRE_K; ++i) {
        if (s_kept >= POST_K) break;
        if (sup[i] == 0) {
            if (t == 0) s_list[s_kept] = i;
            const float bi0 = bx0[i], bi1 = bx1[i], bi2 = bx2[i], bi3 = bx3[i];
            const float ai = ar[i];
            const int ci = clsA[i];
#pragma unroll
            for (int u = 0; u < 4; ++u) {
                const int jj = t + u * 256;
                if (jj > i && jj < PRE_K && sup[jj] == 0 && clsA[jj] == ci) {
                    float xx1 = fmaxf(bi0, bx0[jj]);
                    float yy1 = fmaxf(bi1, bx1[jj]);
                    float xx2 = fminf(bi2, bx2[jj]);
                    float yy2 = fminf(bi3, bx3[jj]);
                    float iw = fmaxf(xx2 - xx1, 0.0f);
                    float ih = fmaxf(yy2 - yy1, 0.0f);
                    float inter = iw * ih;
                    float iou = inter / (ai + ar[jj] - inter + 1e-9f);
                    if (iou > NMS_T) sup[jj] = 1;
                }
            }
            if (t == 0) s_kept = s_kept + 1;
        }
        __syncthreads();
    }
    __syncthreads();
    if (t < POST_K) {
        float o0 = 0.f, o1 = 0.f, o2 = 0.f, o3 = 0.f, o4 = 0.f, lab = 0.f;
        if (t < s_kept) {
            int i = s_list[t];
            o0 = bx0[i]; o1 = bx1[i]; o2 = bx2[i]; o3 = bx3[i];
            o4 = scv[i]; lab = (float)clsA[i];
        }
        float* dets = out + (size_t)(n * POST_K + t) * 5;
        dets[0] = o0; dets[1] = o1; dets[2] = o2; dets[3] = o3; dets[4] = o4;
        out[(size_t)NI * POST_K * 5 + (size_t)n * POST_K + t] = lab;
    }
}

// ---------------------------------------------------------------------------
extern "C" void kernel_launch(void* const* d_in, const int* in_sizes, int n_in,
                              void* d_out, int out_size, void* d_ws, size_t ws_size,
                              hipStream_t stream) {
    const float* reg  = (const float*)d_in[0];
    const float* ctr  = (const float*)d_in[1];
    const float* cls  = (const float*)d_in[2];
    const float* anch = (const float*)d_in[3];
    float* out = (float*)d_out;

    char* ws = (char*)d_ws;
    unsigned long long* cand = (unsigned long long*)ws;            // 2 MB
    size_t off = (size_t)NI * CAP * 8;
    uint32_t* ghist = (uint32_t*)(ws + off);                       // 64 KB
    off += (size_t)NI * HSIZE * 4;
    uint32_t* cnt = (uint32_t*)(ws + off);                         // 8 words (contig w/ ghist)
    off += NI * 4;
    uint32_t* thr = (uint32_t*)(ws + off);
    off += 32;
    float* cv = (float*)(ws + off);  off += (size_t)NI * LL * 4;   // 0.8 MB
    float* X1 = (float*)(ws + off); off += NI * 1024 * 4;
    float* Y1 = (float*)(ws + off); off += NI * 1024 * 4;
    float* X2 = (float*)(ws + off); off += NI * 1024 * 4;
    float* Y2 = (float*)(ws + off); off += NI * 1024 * 4;
    float* AR = (float*)(ws + off); off += NI * 1024 * 4;
    float* SC = (float*)(ws + off); off += NI * 1024 * 4;
    int*   CL = (int*)(ws + off);   off += NI * 1024 * 4;

    k_ctr    <<<64,        256, 0, stream>>>(ctr, cv, ghist);      // also zeros ghist+cnt
    k_hist   <<<NI * BPI3, 256, 0, stream>>>(cls, cv, ghist);
    k_thresh <<<NI,        256, 0, stream>>>(ghist, thr);
    k_collect<<<NI * BPI3, 256, 0, stream>>>(cls, cv, thr, cnt, cand);
    k_select <<<NI,       1024, 0, stream>>>(cand, cnt, reg, anch, X1, Y1, X2, Y2, AR, SC, CL);
    k_nms    <<<NI,        256, 0, stream>>>(X1, Y1, X2, Y2, AR, SC, CL, out);
}